// Round 9
// baseline (95.574 us; speedup 1.0000x reference)
//
#include <hip/hip_runtime.h>

#define FR 3
#define KS 7
#define TLX 64
#define TLY 32
#define PPT 4                 // pixel rows per thread
#define HX (TLX + 2*FR)       // 70
#define HY (TLY + FR)         // 35 (top halo only; half-kernel has dy<=0)
#define LSTR 72               // LDS row stride (floats); 288B rows
#define CSTR (HY * LSTR)      // channel stride in LDS floats
#define IMG_H 512
#define IMG_W 512
#define NB 8
#define NC 3
#define GXB (IMG_W / TLX)     // 8
#define GYB (IMG_H / TLY)     // 16
#define NMAIN (GXB * GYB * NB)    // 1024
#define RIM_PER_IMG 6108          // 512^2 - 506^2
#define NRIM_THREADS (RIM_PER_IMG * NB)          // 48864
#define NRIM_BLK ((NRIM_THREADS + 255) / 256)    // 191
#define NBLK_A (NMAIN + NRIM_BLK)                // 1215
#define NPART NBLK_A

// exp(-50*s) = 2^(-K2*s), K2 = 50*log2(e)=72.13475204444817. Main kernel
// pre-scales inputs by K=sqrt(K2) so exp2 arg is just -(sum of squared diffs).
#define KSC 8.493218f
#define K2F 72.134752f

typedef float v2f __attribute__((ext_vector_type(2)));
__device__ __forceinline__ v2f mk2(float a, float b) { v2f r; r.x = a; r.y = b; return r; }

constexpr double g1d[KS] = {0.011108996538242306, 0.1353352832366127,
                            0.6065306597126334,   1.0,
                            0.6065306597126334,   0.1353352832366127,
                            0.011108996538242306};
constexpr double SUMG = 1.0 + 2.0 * (0.011108996538242306 + 0.1353352832366127
                                     + 0.6065306597126334);
constexpr double INVN = 1.0 / (SUMG * SUMG);
constexpr double KD   = 8.493218;   // must match KSC
constexpr double WPAIR = 2.0 * INVN / KD;   // pair-doubled, un-scaled, normalized

__device__ __forceinline__ int refl(int i, int n) {
    i = (i < 0) ? -i : i;
    return (i >= n) ? (2*n - 2 - i) : i;
}

// One half-space tap for a pixel pair: t += sumabs(d) * exp2(-ss(d)) * glw
__device__ __forceinline__ void tap(v2f& t, v2f c0, v2f c1, v2f c2,
                                    v2f w0, v2f w1, v2f w2, float glw) {
    v2f d0 = c0 - w0;
    v2f d1 = c1 - w1;
    v2f d2 = c2 - w2;
    v2f s  = d0 * d0;
    s = __builtin_elementwise_fma(d1, d1, s);
    s = __builtin_elementwise_fma(d2, d2, s);
    v2f e;
    e.x = __builtin_amdgcn_exp2f(-s.x);
    e.y = __builtin_amdgcn_exp2f(-s.y);
    v2f sa;                      // scalar adds: |x| folds as VOP3 modifier
    sa.x = fabsf(d0.x) + fabsf(d1.x);
    sa.x += fabsf(d2.x);
    sa.y = fabsf(d0.y) + fabsf(d1.y);
    sa.y += fabsf(d2.y);
    t = __builtin_elementwise_fma(sa, e * glw, t);
}

// Fused kernel. Blocks [0, NRIM_BLK) = rim path; rest = main path.
//
// Main path is mask-free: every half-space tap is counted x2 with the
// reflected halo value, weights are uniform compile-time scalars. The rim
// path carries the boundary correction with a per-(k,l) SIGN:
//   True = 2*sum_{neghalf} V  +  sum_{OOB,poshalf} V  -  sum_{OOB,neghalf} V
// Verified exact by harness (rounds 1-6, absmax 0.0).
//
// R6 lesson: fully-unrolled main body was ~35KB straight-line code ->
// I$ thrash (explains instruction-count-linear timing + scheduling
// insensitivity). This version RE-ROLLS the main k-loop (3 trips, ~1KB
// body); total code ~6KB fits the 32KB I$. No __constant__ globals, no
// device lambdas (R7/R8 loader-failure suspects).
__global__ __launch_bounds__(256, 4) void blt_fused(const float* __restrict__ in,
                                                    float* __restrict__ partial) {
    __shared__ __attribute__((aligned(16))) float sm[NC][HY][LSTR];  // 30240 B
    __shared__ float wsum[4];
    const int tid = threadIdx.x;
    float a = 0.0f;

    if (blockIdx.x >= NRIM_BLK) {
        // ---- main path ----
        const int bid = blockIdx.x - NRIM_BLK;
        const int b   = bid >> 7;            // 128 blocks per image (8 x 16)
        const int rem = bid & 127;
        const int by  = (rem >> 3) * TLY;
        const int bx  = (rem & 7) * TLX;
        const int tx  = tid & 31;            // pair-column 0..31
        const int ty  = tid >> 5;            // 0..7 -> 4-row strip
        const float* base = in + (size_t)b * NC * IMG_H * IMG_W;

        // Stage reflect-padded halo tile (top+side), pre-scaled by K.
        for (int idx = tid; idx < HY * HX; idx += 256) {
            int ly = idx / HX;
            int lx = idx - ly * HX;
            int gy = refl(by + ly - FR, IMG_H);
            int gx = refl(bx + lx - FR, IMG_W);
            #pragma unroll
            for (int c = 0; c < NC; ++c)
                sm[c][ly][lx] = base[(c * IMG_H + gy) * IMG_W + gx] * KSC;
        }
        __syncthreads();

        const int r0 = ty * PPT;
        v2f cc[PPT][NC];
        v2f acc[PPT];

        // Phase A: center rows (dy==0). Capture centers + 3 left-column taps.
        #pragma unroll
        for (int i = 0; i < PPT; ++i) {
            const float* rp0 = &sm[0][r0 + i + FR][2 * tx];
            v2f p0[NC], p1[NC], q1[NC];
            #pragma unroll
            for (int c = 0; c < NC; ++c) {
                const float* rp = rp0 + c * CSTR;
                p0[c] = *reinterpret_cast<const v2f*>(rp + 0);
                p1[c] = *reinterpret_cast<const v2f*>(rp + 2);
                q1[c] = mk2(rp[1], rp[2]);           // ds_read2_b32
                cc[i][c] = mk2(rp[3], rp[4]);        // ds_read2_b32
            }
            v2f t = mk2(0.0f, 0.0f);
            tap(t, cc[i][0], cc[i][1], cc[i][2], p0[0], p0[1], p0[2], (float)(g1d[0] * WPAIR));
            tap(t, cc[i][0], cc[i][1], cc[i][2], q1[0], q1[1], q1[2], (float)(g1d[1] * WPAIR));
            tap(t, cc[i][0], cc[i][1], cc[i][2], p1[0], p1[1], p1[2], (float)(g1d[2] * WPAIR));
            acc[i] = t;                              // g1d[FR] == 1.0
        }

        // Phase B: dy = -3..-1 rows, full 7 columns. ROLLED k-loop (small code).
        #pragma unroll
        for (int i = 0; i < PPT; ++i) {
            #pragma unroll 1
            for (int k = 0; k < FR; ++k) {
                const float* rp0 = &sm[0][r0 + i + k][2 * tx];
                v2f w[NC][KS];
                #pragma unroll
                for (int c = 0; c < NC; ++c) {
                    const float* rp = rp0 + c * CSTR;
                    w[c][0] = *reinterpret_cast<const v2f*>(rp + 0);
                    w[c][2] = *reinterpret_cast<const v2f*>(rp + 2);
                    w[c][4] = *reinterpret_cast<const v2f*>(rp + 4);
                    w[c][6] = *reinterpret_cast<const v2f*>(rp + 6);
                    w[c][1] = mk2(rp[1], rp[2]);
                    w[c][3] = mk2(rp[3], rp[4]);
                    w[c][5] = mk2(rp[5], rp[6]);
                }
                v2f t = mk2(0.0f, 0.0f);
                #pragma unroll
                for (int l = 0; l < KS; ++l)
                    tap(t, cc[i][0], cc[i][1], cc[i][2],
                        w[0][l], w[1][l], w[2][l], (float)(g1d[l] * WPAIR));
                // k is wave-uniform; if-chain -> scalar selects, no table.
                const float gk = (k == 0) ? (float)g1d[0]
                               : ((k == 1) ? (float)g1d[1] : (float)g1d[2]);
                acc[i] = __builtin_elementwise_fma(t, mk2(gk, gk), acc[i]);
            }
        }

        v2f av = (acc[0] + acc[1]) + (acc[2] + acc[3]);
        a = av.x + av.y;
    } else {
        // ---- rim path: signed correction for taps whose partner is OOB ----
        // (byte-identical to the R4 known-good form)
        const int idx = blockIdx.x * 256 + tid;
        if (idx < NRIM_THREADS) {
            const int b = idx / RIM_PER_IMG;
            int r = idx - b * RIM_PER_IMG;
            int y, x;
            if (r < 3 * IMG_W) { y = r >> 9; x = r & (IMG_W - 1); }
            else if (r < 6 * IMG_W) { r -= 3 * IMG_W; y = (IMG_H - 3) + (r >> 9); x = r & (IMG_W - 1); }
            else if (r < 6 * IMG_W + 3 * (IMG_H - 6)) { r -= 6 * IMG_W; y = 3 + r / 3; x = r - 3 * (r / 3); }
            else { r -= 6 * IMG_W + 3 * (IMG_H - 6); y = 3 + r / 3; x = (IMG_W - 3) + (r - 3 * (r / 3)); }

            const float* base = in + (size_t)b * NC * IMG_H * IMG_W;
            const float cc0 = base[(0 * IMG_H + y) * IMG_W + x];
            const float cc1 = base[(1 * IMG_H + y) * IMG_W + x];
            const float cc2 = base[(2 * IMG_H + y) * IMG_W + x];

            #pragma unroll
            for (int k = 0; k < KS; ++k) {
                #pragma unroll
                for (int l = 0; l < KS; ++l) {
                    if (k == FR && l == FR) continue;
                    int qy = y + k - FR, qx = x + l - FR;
                    bool oob = ((unsigned)qy >= (unsigned)IMG_H) | ((unsigned)qx >= (unsigned)IMG_W);
                    if (oob) {
                        int ry = refl(qy, IMG_H), rx = refl(qx, IMG_W);
                        float v0 = base[(0 * IMG_H + ry) * IMG_W + rx];
                        float v1 = base[(1 * IMG_H + ry) * IMG_W + rx];
                        float v2 = base[(2 * IMG_H + ry) * IMG_W + rx];
                        float d0 = cc0 - v0, d1 = cc1 - v1, d2 = cc2 - v2;
                        float s = d0 * d0;
                        s = fmaf(d1, d1, s);
                        s = fmaf(d2, d2, s);
                        float e = __builtin_amdgcn_exp2f(-(K2F * s));
                        float sa = fabsf(d0) + fabsf(d1) + fabsf(d2);
                        // +1 for poshalf (dy>0 or dy==0,dx>0): main never counts.
                        // -1 for neghalf: main double-counted them.
                        const bool pos = (k > FR) || (k == FR && l > FR);
                        const float wkl = (float)(g1d[k] * g1d[l] * INVN * (pos ? 1.0 : -1.0));
                        a = fmaf(sa, e * wkl, a);
                    }
                }
            }
        }
        __syncthreads();
    }

    // Block reduction -> one partial per block.
    #pragma unroll
    for (int off = 32; off > 0; off >>= 1)
        a += __shfl_down(a, off, 64);
    if ((tid & 63) == 0) wsum[tid >> 6] = a;
    __syncthreads();
    if (tid == 0)
        partial[blockIdx.x] = wsum[0] + wsum[1] + wsum[2] + wsum[3];
}

__global__ __launch_bounds__(256) void finalize_kernel(const float* __restrict__ partial,
                                                       float* __restrict__ out) {
    __shared__ float wsum[4];
    const int tid = threadIdx.x;
    float a = 0.0f;
    for (int i = tid; i < NPART; i += 256) a += partial[i];
    #pragma unroll
    for (int off = 32; off > 0; off >>= 1)
        a += __shfl_down(a, off, 64);
    if ((tid & 63) == 0) wsum[tid >> 6] = a;
    __syncthreads();
    if (tid == 0)
        out[0] = (wsum[0] + wsum[1] + wsum[2] + wsum[3]) / (float)(NB * NC * IMG_H * IMG_W);
}

extern "C" void kernel_launch(void* const* d_in, const int* in_sizes, int n_in,
                              void* d_out, int out_size, void* d_ws, size_t ws_size,
                              hipStream_t stream) {
    const float* in = (const float*)d_in[0];
    float* out = (float*)d_out;
    float* ws  = (float*)d_ws;      // NPART partials; every slot written each call

    blt_fused<<<NBLK_A, 256, 0, stream>>>(in, ws);
    finalize_kernel<<<1, 256, 0, stream>>>(ws, out);
}

// Round 10
// 90.207 us; speedup vs baseline: 1.0595x; 1.0595x over previous
//
#include <hip/hip_runtime.h>

#define FR 3
#define KS 7
#define TLX 64
#define TLY 32
#define PPT 4                 // pixel rows per thread
#define HX (TLX + 2*FR)       // 70
#define HY (TLY + FR)         // 35 (top halo only; half-kernel has dy<=0)
#define LSTR 72               // LDS row stride (floats); 288B rows
#define IMG_H 512
#define IMG_W 512
#define NB 8
#define NC 3
#define GXB (IMG_W / TLX)     // 8
#define GYB (IMG_H / TLY)     // 16
#define NMAIN (GXB * GYB * NB)    // 1024
#define RIM_PER_IMG 6108          // 512^2 - 506^2
#define NRIM_THREADS (RIM_PER_IMG * NB)          // 48864
#define NRIM_BLK ((NRIM_THREADS + 255) / 256)    // 191
#define NBLK_A (NMAIN + NRIM_BLK)                // 1215
#define NPART NBLK_A

// exp(-50*s) = 2^(-K2*s), K2 = 50*log2(e)=72.13475204444817. Main kernel
// pre-scales inputs by K=sqrt(K2) so exp2 arg is just -(sum of squared diffs).
#define KSC 8.493218f
#define K2F 72.134752f

typedef float v2f __attribute__((ext_vector_type(2)));
__device__ __forceinline__ v2f mk2(float a, float b) { v2f r; r.x = a; r.y = b; return r; }

constexpr double g1d[KS] = {0.011108996538242306, 0.1353352832366127,
                            0.6065306597126334,   1.0,
                            0.6065306597126334,   0.1353352832366127,
                            0.011108996538242306};
constexpr double SUMG = 1.0 + 2.0 * (0.011108996538242306 + 0.1353352832366127
                                     + 0.6065306597126334);
constexpr double INVN = 1.0 / (SUMG * SUMG);
constexpr double KD   = 8.493218;   // must match KSC
constexpr double WPAIR = 2.0 * INVN / KD;   // pair-doubled, un-scaled, normalized

__device__ __forceinline__ int refl(int i, int n) {
    i = (i < 0) ? -i : i;
    return (i >= n) ? (2*n - 2 - i) : i;
}

// Fused kernel. Blocks [0, NRIM_BLK) = rim path; rest = main path.
//
// Main path is mask-free: every half-space tap is counted x2 with the
// reflected halo value, weights are uniform compile-time scalars. The rim
// path carries the boundary correction with a per-(k,l) SIGN:
//   True = 2*sum_{neghalf} V  +  sum_{OOB,poshalf} V  -  sum_{OOB,neghalf} V
// (neghalf = dy<0 or (dy==0 and dx<0), i.e. what main enumerates.)
// Verified exact by harness (rounds 1-9, absmax 0.0).
//
// This is the empirical best across 9 measured variants (88.65us):
// fully-unrolled main body, 7 windows serving 16 (row,k) uses, read2-idiom
// odd windows, scalar abs-adds (|x| folds as VOP3 modifier), lb(256,4).
// Measured-worse neighbors: explicit reg double-buffer pipeline (+2.3us),
// re-rolled k-loop (+6.9us), TLY=16 lb(256,8) (+7.6us), v4f quad (+6us),
// fused single-pass finalize (+86us).
__global__ __launch_bounds__(256, 4) void blt_fused(const float* __restrict__ in,
                                                    float* __restrict__ partial) {
    __shared__ __attribute__((aligned(16))) float sm[NC][HY][LSTR];  // 30240 B
    __shared__ float wsum[4];
    const int tid = threadIdx.x;
    float a = 0.0f;

    if (blockIdx.x >= NRIM_BLK) {
        // ---- main path ----
        const int bid = blockIdx.x - NRIM_BLK;
        const int b   = bid >> 7;            // 128 blocks per image (8 x 16)
        const int rem = bid & 127;
        const int by  = (rem >> 3) * TLY;
        const int bx  = (rem & 7) * TLX;
        const int tx  = tid & 31;            // pair-column 0..31
        const int ty  = tid >> 5;            // 0..7 -> 4-row strip
        const float* base = in + (size_t)b * NC * IMG_H * IMG_W;

        // Stage reflect-padded halo tile (top+side), pre-scaled by K.
        for (int idx = tid; idx < HY * HX; idx += 256) {
            int ly = idx / HX;
            int lx = idx - ly * HX;
            int gy = refl(by + ly - FR, IMG_H);
            int gx = refl(bx + lx - FR, IMG_W);
            #pragma unroll
            for (int c = 0; c < NC; ++c)
                sm[c][ly][lx] = base[(c * IMG_H + gy) * IMG_W + gx] * KSC;
        }
        __syncthreads();

        const int r0 = ty * PPT;
        v2f cc[PPT][NC];
        v2f acc[PPT];
        #pragma unroll
        for (int i = 0; i < PPT; ++i) acc[i] = mk2(0.0f, 0.0f);

        // Descending halo rows: pixel-row i's center row (rr=i+3) comes first,
        // so centers are captured from the row window (no extra reads).
        #pragma unroll
        for (int rr = PPT + FR - 1; rr >= 0; --rr) {   // 7 windows
            v2f wp[NC][KS];
            #pragma unroll
            for (int c = 0; c < NC; ++c) {
                const float* rp = &sm[c][r0 + rr][2 * tx];
                // Even windows: aligned b64 reads.
                wp[c][0] = *reinterpret_cast<const v2f*>(rp + 0);
                wp[c][2] = *reinterpret_cast<const v2f*>(rp + 2);
                wp[c][4] = *reinterpret_cast<const v2f*>(rp + 4);
                wp[c][6] = *reinterpret_cast<const v2f*>(rp + 6);
                // Odd windows: adjacent b32 pairs (ds_read2_b32 idiom).
                wp[c][1] = mk2(rp[1], rp[2]);
                wp[c][3] = mk2(rp[3], rp[4]);
                wp[c][5] = mk2(rp[5], rp[6]);
            }
            #pragma unroll
            for (int i = 0; i < PPT; ++i) {
                const int k = rr - i;                 // dy + 3
                if (k < 0 || k > FR) continue;        // compile-time
                if (k == FR) {                        // center row: capture centers
                    cc[i][0] = wp[0][3];
                    cc[i][1] = wp[1][3];
                    cc[i][2] = wp[2][3];
                }
                const int lmax = (k == FR) ? FR : KS; // dy==0: left cols only
                v2f t = mk2(0.0f, 0.0f);
                #pragma unroll
                for (int l = 0; l < KS; ++l) {
                    if (l >= lmax) continue;          // compile-time
                    v2f d0 = cc[i][0] - wp[0][l];
                    v2f d1 = cc[i][1] - wp[1][l];
                    v2f d2 = cc[i][2] - wp[2][l];
                    v2f s  = d0 * d0;
                    s = __builtin_elementwise_fma(d1, d1, s);
                    s = __builtin_elementwise_fma(d2, d2, s);
                    v2f e;
                    e.x = __builtin_amdgcn_exp2f(-s.x);
                    e.y = __builtin_amdgcn_exp2f(-s.y);
                    // Scalar abs-adds: VOP3 v_add_f32 folds |x| free.
                    v2f sa;
                    sa.x = fabsf(d0.x) + fabsf(d1.x);
                    sa.x += fabsf(d2.x);
                    sa.y = fabsf(d0.y) + fabsf(d1.y);
                    sa.y += fabsf(d2.y);
                    t = __builtin_elementwise_fma(sa, e * (float)(g1d[l] * WPAIR), t);
                }
                acc[i] = __builtin_elementwise_fma(t, mk2((float)g1d[k], (float)g1d[k]), acc[i]);
            }
        }
        v2f av = (acc[0] + acc[1]) + (acc[2] + acc[3]);
        a = av.x + av.y;
    } else {
        // ---- rim path: signed correction for taps whose partner is OOB ----
        const int idx = blockIdx.x * 256 + tid;
        if (idx < NRIM_THREADS) {
            const int b = idx / RIM_PER_IMG;
            int r = idx - b * RIM_PER_IMG;
            int y, x;
            if (r < 3 * IMG_W) { y = r >> 9; x = r & (IMG_W - 1); }
            else if (r < 6 * IMG_W) { r -= 3 * IMG_W; y = (IMG_H - 3) + (r >> 9); x = r & (IMG_W - 1); }
            else if (r < 6 * IMG_W + 3 * (IMG_H - 6)) { r -= 6 * IMG_W; y = 3 + r / 3; x = r - 3 * (r / 3); }
            else { r -= 6 * IMG_W + 3 * (IMG_H - 6); y = 3 + r / 3; x = (IMG_W - 3) + (r - 3 * (r / 3)); }

            const float* base = in + (size_t)b * NC * IMG_H * IMG_W;
            const float cc0 = base[(0 * IMG_H + y) * IMG_W + x];
            const float cc1 = base[(1 * IMG_H + y) * IMG_W + x];
            const float cc2 = base[(2 * IMG_H + y) * IMG_W + x];

            #pragma unroll
            for (int k = 0; k < KS; ++k) {
                #pragma unroll
                for (int l = 0; l < KS; ++l) {
                    if (k == FR && l == FR) continue;
                    int qy = y + k - FR, qx = x + l - FR;
                    bool oob = ((unsigned)qy >= (unsigned)IMG_H) | ((unsigned)qx >= (unsigned)IMG_W);
                    if (oob) {
                        int ry = refl(qy, IMG_H), rx = refl(qx, IMG_W);
                        float v0 = base[(0 * IMG_H + ry) * IMG_W + rx];
                        float v1 = base[(1 * IMG_H + ry) * IMG_W + rx];
                        float v2 = base[(2 * IMG_H + ry) * IMG_W + rx];
                        float d0 = cc0 - v0, d1 = cc1 - v1, d2 = cc2 - v2;
                        float s = d0 * d0;
                        s = fmaf(d1, d1, s);
                        s = fmaf(d2, d2, s);
                        float e = __builtin_amdgcn_exp2f(-(K2F * s));
                        float sa = fabsf(d0) + fabsf(d1) + fabsf(d2);
                        // +1 for poshalf (dy>0 or dy==0,dx>0): main never counts.
                        // -1 for neghalf: main double-counted them.
                        const bool pos = (k > FR) || (k == FR && l > FR);
                        const float wkl = (float)(g1d[k] * g1d[l] * INVN * (pos ? 1.0 : -1.0));
                        a = fmaf(sa, e * wkl, a);
                    }
                }
            }
        }
        __syncthreads();
    }

    // Block reduction -> one partial per block.
    #pragma unroll
    for (int off = 32; off > 0; off >>= 1)
        a += __shfl_down(a, off, 64);
    if ((tid & 63) == 0) wsum[tid >> 6] = a;
    __syncthreads();
    if (tid == 0)
        partial[blockIdx.x] = wsum[0] + wsum[1] + wsum[2] + wsum[3];
}

__global__ __launch_bounds__(256) void finalize_kernel(const float* __restrict__ partial,
                                                       float* __restrict__ out) {
    __shared__ float wsum[4];
    const int tid = threadIdx.x;
    float a = 0.0f;
    for (int i = tid; i < NPART; i += 256) a += partial[i];
    #pragma unroll
    for (int off = 32; off > 0; off >>= 1)
        a += __shfl_down(a, off, 64);
    if ((tid & 63) == 0) wsum[tid >> 6] = a;
    __syncthreads();
    if (tid == 0)
        out[0] = (wsum[0] + wsum[1] + wsum[2] + wsum[3]) / (float)(NB * NC * IMG_H * IMG_W);
}

extern "C" void kernel_launch(void* const* d_in, const int* in_sizes, int n_in,
                              void* d_out, int out_size, void* d_ws, size_t ws_size,
                              hipStream_t stream) {
    const float* in = (const float*)d_in[0];
    float* out = (float*)d_out;
    float* ws  = (float*)d_ws;      // NPART partials; every slot written each call

    blt_fused<<<NBLK_A, 256, 0, stream>>>(in, ws);
    finalize_kernel<<<1, 256, 0, stream>>>(ws, out);
}